// Round 4
// baseline (798.007 us; speedup 1.0000x reference)
//
#include <hip/hip_runtime.h>

#define TOTAL_WORDS 10000
#define EMBED_LEN 100
#define SEQ_LEN 80
#define BATCH 4096
#define UNITS 64

// ---------- fast activations (no NaN at saturation) ----------
__device__ __forceinline__ float fast_sigmoid(float x) {
    // 1/(1+2^(-x*log2e)); x->+inf: rcp(1)=1; x->-inf: rcp(inf)=0
    return __builtin_amdgcn_rcpf(1.0f + __builtin_amdgcn_exp2f(-1.4426950408889634f * x));
}
__device__ __forceinline__ float fast_tanh(float x) {
    // 2*sigmoid(2x)-1; saturates to +/-1 without inf/inf
    return fmaf(2.0f, __builtin_amdgcn_rcpf(1.0f + __builtin_amdgcn_exp2f(-2.8853900817779268f * x)), -1.0f);
}
__device__ __forceinline__ float rl(float v, int k) {
    return __uint_as_float(__builtin_amdgcn_readlane(__float_as_uint(v), (unsigned)k));
}

// ---------- precompute embW[v][u*4+g] = emb[v]@W1[:, g*64+u] + b1[g*64+u] ----------
__global__ __launch_bounds__(256) void embW_kernel(
    const float* __restrict__ emb, const float* __restrict__ W1,
    const float* __restrict__ b1, float* __restrict__ embWr)
{
    const int v = blockIdx.x;          // word id
    const int j = threadIdx.x;         // j = g*64 + u (original column)
    float acc = b1[j];
    const float* er = emb + v * EMBED_LEN;
    #pragma unroll 4
    for (int k = 0; k < EMBED_LEN; ++k)
        acc = fmaf(er[k], W1[k * 256 + j], acc);
    const int u = j & 63, g = j >> 6;
    embWr[v * 256 + u * 4 + g] = acc;
}

// ---------- repack U1,W2,U2 to [k][u*4+g]; b2 to [u*4+g] ----------
__global__ __launch_bounds__(256) void repack_kernel(
    const float* __restrict__ U1, const float* __restrict__ W2,
    const float* __restrict__ U2, const float* __restrict__ b2,
    float* __restrict__ U1r, float* __restrict__ W2r,
    float* __restrict__ U2r, float* __restrict__ b2r)
{
    const int idx = blockIdx.x * 256 + threadIdx.x;  // 0..16383
    const int k = idx >> 8;
    const int j = idx & 255;
    const int u = j & 63, g = j >> 6;
    const int dst = k * 256 + u * 4 + g;
    U1r[dst] = U1[idx];
    W2r[dst] = W2[idx];
    U2r[dst] = U2[idx];
    if (idx < 256) b2r[u * 4 + g] = b2[j];
}

// ---------- main recurrence: 1 wave = 4 samples; lane u owns unit u ----------
__global__ __launch_bounds__(256) void lstm_main(
    const int*   __restrict__ tokens,
    const float* __restrict__ embWr,
    const float* __restrict__ U1r,
    const float* __restrict__ W2r,
    const float* __restrict__ U2r,
    const float* __restrict__ b2r,
    const float* __restrict__ Wo,
    const float* __restrict__ bo,
    float*       __restrict__ out)
{
    const int lane = threadIdx.x & 63;
    const int wave = threadIdx.x >> 6;
    const int b0 = (blockIdx.x * 4 + wave) * 4;   // 4 samples per wave

    float h1[4] = {0.f, 0.f, 0.f, 0.f}, c1[4] = {0.f, 0.f, 0.f, 0.f};
    float h2[4] = {0.f, 0.f, 0.f, 0.f}, c2[4] = {0.f, 0.f, 0.f, 0.f};

    const float4 b2v = *(const float4*)(b2r + lane * 4);

    // prefetch t=0 gathers
    float4 xa[4];
    #pragma unroll
    for (int b = 0; b < 4; ++b) {
        const int tok = tokens[(b0 + b) * SEQ_LEN];
        xa[b] = *(const float4*)(embWr + (size_t)tok * 256 + lane * 4);
    }

    for (int t = 0; t < SEQ_LEN; ++t) {
        // layer-1 accumulators seeded by gathered x@W1+b1
        float4 a1[4];
        #pragma unroll
        for (int b = 0; b < 4; ++b) a1[b] = xa[b];

        // prefetch next step's gather (clamped; last iter re-loads t=79, unused)
        const int tn = (t + 1 < SEQ_LEN) ? t + 1 : SEQ_LEN - 1;
        #pragma unroll
        for (int b = 0; b < 4; ++b) {
            const int tok = tokens[(b0 + b) * SEQ_LEN + tn];
            xa[b] = *(const float4*)(embWr + (size_t)tok * 256 + lane * 4);
        }

        // ---- layer 1: z1 += h1 @ U1 ----
        #pragma unroll 8
        for (int k = 0; k < UNITS; ++k) {
            const float4 w = *(const float4*)(U1r + k * 256 + lane * 4);
            #pragma unroll
            for (int b = 0; b < 4; ++b) {
                const float hk = rl(h1[b], k);
                a1[b].x = fmaf(hk, w.x, a1[b].x);
                a1[b].y = fmaf(hk, w.y, a1[b].y);
                a1[b].z = fmaf(hk, w.z, a1[b].z);
                a1[b].w = fmaf(hk, w.w, a1[b].w);
            }
        }
        #pragma unroll
        for (int b = 0; b < 4; ++b) {
            const float ii = fast_sigmoid(a1[b].x);
            const float ff = fast_sigmoid(a1[b].y);
            const float gg = fast_tanh(a1[b].z);
            const float oo = fast_sigmoid(a1[b].w);
            c1[b] = fmaf(ff, c1[b], ii * gg);
            h1[b] = oo * fast_tanh(c1[b]);
        }

        // ---- layer 2: z2 = b2 + h1 @ W2 + h2 @ U2 ----
        float4 a2[4];
        #pragma unroll
        for (int b = 0; b < 4; ++b) a2[b] = b2v;

        #pragma unroll 4
        for (int k = 0; k < UNITS; ++k) {
            const float4 w = *(const float4*)(W2r + k * 256 + lane * 4);
            const float4 u = *(const float4*)(U2r + k * 256 + lane * 4);
            #pragma unroll
            for (int b = 0; b < 4; ++b) {
                const float h1k = rl(h1[b], k);
                const float h2k = rl(h2[b], k);
                a2[b].x = fmaf(h1k, w.x, a2[b].x);
                a2[b].y = fmaf(h1k, w.y, a2[b].y);
                a2[b].z = fmaf(h1k, w.z, a2[b].z);
                a2[b].w = fmaf(h1k, w.w, a2[b].w);
                a2[b].x = fmaf(h2k, u.x, a2[b].x);
                a2[b].y = fmaf(h2k, u.y, a2[b].y);
                a2[b].z = fmaf(h2k, u.z, a2[b].z);
                a2[b].w = fmaf(h2k, u.w, a2[b].w);
            }
        }
        #pragma unroll
        for (int b = 0; b < 4; ++b) {
            const float ii = fast_sigmoid(a2[b].x);
            const float ff = fast_sigmoid(a2[b].y);
            const float gg = fast_tanh(a2[b].z);
            const float oo = fast_sigmoid(a2[b].w);
            c2[b] = fmaf(ff, c2[b], ii * gg);
            h2[b] = oo * fast_tanh(c2[b]);
        }
    }

    // ---- output: sigmoid(h2 @ Wo + bo) ----
    const float wo = Wo[lane];
    const float bov = bo[0];
    #pragma unroll
    for (int b = 0; b < 4; ++b) {
        float v = h2[b] * wo;
        #pragma unroll
        for (int m = 32; m > 0; m >>= 1) v += __shfl_xor(v, m, 64);
        if (lane == 0) out[b0 + b] = fast_sigmoid(v + bov);
    }
}

extern "C" void kernel_launch(void* const* d_in, const int* in_sizes, int n_in,
                              void* d_out, int out_size, void* d_ws, size_t ws_size,
                              hipStream_t stream) {
    const int*   tokens = (const int*)  d_in[0];
    const float* emb    = (const float*)d_in[1];
    const float* W1     = (const float*)d_in[2];
    const float* U1     = (const float*)d_in[3];
    const float* b1     = (const float*)d_in[4];   // folded into embW
    const float* W2     = (const float*)d_in[5];
    const float* U2     = (const float*)d_in[6];
    const float* b2     = (const float*)d_in[7];
    const float* Wo     = (const float*)d_in[8];
    const float* bo     = (const float*)d_in[9];
    float* out = (float*)d_out;

    char* ws = (char*)d_ws;
    float* embWr = (float*)(ws);                                   // 10,240,000 B
    float* U1r   = (float*)(ws + 10240000);                        // 65,536 B
    float* W2r   = (float*)(ws + 10240000 + 65536);                // 65,536 B
    float* U2r   = (float*)(ws + 10240000 + 2 * 65536);            // 65,536 B
    float* b2r   = (float*)(ws + 10240000 + 3 * 65536);            // 1,024 B
    (void)b1; (void)in_sizes; (void)n_in; (void)out_size; (void)ws_size;

    embW_kernel<<<TOTAL_WORDS, 256, 0, stream>>>(emb, W1, b1, embWr);
    repack_kernel<<<64, 256, 0, stream>>>(U1, W2, U2, b2, U1r, W2r, U2r, b2r);
    lstm_main<<<BATCH / 16, 256, 0, stream>>>(tokens, embWr, U1r, W2r, U2r, b2r, Wo, bo, out);
}

// Round 7
// 450.689 us; speedup vs baseline: 1.7706x; 1.7706x over previous
//
#include <hip/hip_runtime.h>

#define TOTAL_WORDS 10000
#define EMBED_LEN 100
#define SEQ_LEN 80
#define BATCH 4096
#define UNITS 64

typedef __attribute__((ext_vector_type(8))) short short8;
typedef __attribute__((ext_vector_type(4))) float floatx4;

// ---------- fast activations (no NaN at saturation) ----------
__device__ __forceinline__ float fast_sigmoid(float x) {
    return __builtin_amdgcn_rcpf(1.0f + __builtin_amdgcn_exp2f(-1.4426950408889634f * x));
}
__device__ __forceinline__ float fast_tanh(float x) {
    return fmaf(2.0f, __builtin_amdgcn_rcpf(1.0f + __builtin_amdgcn_exp2f(-2.8853900817779268f * x)), -1.0f);
}
// RNE f32->bf16 pair pack (a -> low16, b -> high16)
__device__ __forceinline__ unsigned int pack_bf16x2(float a, float b) {
    unsigned int ua = __float_as_uint(a), ub = __float_as_uint(b);
    ua = (ua + 0x7FFFu + ((ua >> 16) & 1u)) >> 16;
    ub = (ub + 0x7FFFu + ((ub >> 16) & 1u)) & 0xFFFF0000u;
    return ua | ub;
}

// ---------- embW[v][j] = emb[v]@W1[:,j] + b1[j]  (original column order) ----------
__global__ __launch_bounds__(256) void embW_kernel(
    const float* __restrict__ emb, const float* __restrict__ W1,
    const float* __restrict__ b1, float* __restrict__ embW)
{
    const int v = blockIdx.x, j = threadIdx.x;
    float acc = b1[j];
    const float* er = emb + v * EMBED_LEN;
    #pragma unroll 4
    for (int k = 0; k < EMBED_LEN; ++k)
        acc = fmaf(er[k], W1[k * 256 + j], acc);
    embW[v * 256 + j] = acc;
}

// ---------- repack U1,W2,U2 (f32 [64][256]) -> bf16 A-fragment-linear ----------
// frag element e = ((tau*2+kt)*64 + lane)*8 + j8 holds bf16( M[kt*32 + (lane>>4)*8 + j8][tau*16 + (lane&15)] )
// i.e. A = M^T tiles in mfma_f32_16x16x32_bf16 A-fragment order.
__global__ __launch_bounds__(256) void repack_kernel(
    const float* __restrict__ U1, const float* __restrict__ W2,
    const float* __restrict__ U2, unsigned short* __restrict__ wr)
{
    const int e = blockIdx.x * 256 + threadIdx.x;          // 0..16383
    const float* src = (blockIdx.y == 0) ? U1 : ((blockIdx.y == 1) ? W2 : U2);
    const int j8 = e & 7;
    const int l  = (e >> 3) & 63;
    const int kt = (e >> 9) & 1;
    const int tau = e >> 10;
    const int k = kt * 32 + (l >> 4) * 8 + j8;
    const int j = tau * 16 + (l & 15);
    unsigned int u = __float_as_uint(src[k * 256 + j]);
    u = (u + 0x7FFFu + ((u >> 16) & 1u)) >> 16;
    wr[blockIdx.y * 16384 + e] = (unsigned short)u;
}

// ---------- main recurrence: 1 wave = 16 samples; MFMA z^T = W^T @ h^T ----------
// LDS: [0, 98304)        weights bf16 frag-linear (U1 | W2 | U2, 16384 ushorts each)
//      [98304, 100608)   h1 bf16 [16 m][72 u-padded]
//      [100608, 102912)  h2 bf16 [16 m][72 u-padded]
__global__ __launch_bounds__(64, 1) void lstm_main(
    const int*   __restrict__ tokens,
    const float* __restrict__ embW,
    const unsigned short* __restrict__ wr,
    const float* __restrict__ b2,
    const float* __restrict__ Wo,
    const float* __restrict__ bo,
    float*       __restrict__ out)
{
    extern __shared__ unsigned char smem[];
    unsigned short* wlds = (unsigned short*)smem;
    unsigned short* h1b  = (unsigned short*)(smem + 98304);
    unsigned short* h2b  = (unsigned short*)(smem + 100608);

    const int l = threadIdx.x;
    const int m = l & 15, q = l >> 4;
    const int b0 = blockIdx.x * 16;
    const int hrow = m * 72;

    // stage weights global->LDS (one-time): 98304 B = 6144 uint4
    for (int i = l; i < 6144; i += 64)
        ((uint4*)wlds)[i] = ((const uint4*)wr)[i];
    // zero h1b+h2b (contiguous 4608 B = 1152 uints)
    for (int i = l; i < 1152; i += 64)
        ((unsigned int*)h1b)[i] = 0u;
    __syncthreads();

    // b2 fragments held in registers: b2^T[j=tau*16+4q+reg][m] = b2[j]
    floatx4 b2f[16];
    #pragma unroll
    for (int t16 = 0; t16 < 16; ++t16)
        b2f[t16] = *(const floatx4*)(b2 + t16 * 16 + 4 * q);

    float c1[4][4] = {}, c2[4][4] = {}, h2f[4][4] = {};

    // t=0 seed gather (cold) + token prefetch for t=1
    const int tok0 = tokens[(b0 + m) * SEQ_LEN + 0];
    floatx4 xb[16];
    #pragma unroll
    for (int t16 = 0; t16 < 16; ++t16)
        xb[t16] = *(const floatx4*)(embW + (size_t)tok0 * 256 + t16 * 16 + 4 * q);
    int tokN = tokens[(b0 + m) * SEQ_LEN + ((SEQ_LEN > 1) ? 1 : 0)];

    const unsigned short* wU1 = wlds;
    const unsigned short* wW2 = wlds + 16384;
    const unsigned short* wU2 = wlds + 32768;

    for (int t = 0; t < SEQ_LEN; ++t) {
        // consume prefetched seed: acc1 = (x@W1 + b1)^T fragments
        floatx4 acc[16];
        #pragma unroll
        for (int i = 0; i < 16; ++i) acc[i] = xb[i];

        // prefetch x for t+1 (tokN preloaded a full step ago), then token for t+2
        #pragma unroll
        for (int t16 = 0; t16 < 16; ++t16)
            xb[t16] = *(const floatx4*)(embW + (size_t)tokN * 256 + t16 * 16 + 4 * q);
        {
            const int tn2 = (t + 2 < SEQ_LEN) ? t + 2 : SEQ_LEN - 1;
            tokN = tokens[(b0 + m) * SEQ_LEN + tn2];
        }

        // ---- layer 1: acc += U1^T-tiles @ h1^T ----
        {
            const short8 hb0 = *(const short8*)(h1b + hrow + 0  + q * 8);
            const short8 hb1 = *(const short8*)(h1b + hrow + 32 + q * 8);
            #pragma unroll
            for (int tau = 0; tau < 16; ++tau) {
                const short8 a0 = *(const short8*)(wU1 + (tau * 2 + 0) * 512 + l * 8);
                acc[tau] = __builtin_amdgcn_mfma_f32_16x16x32_bf16(a0, hb0, acc[tau], 0, 0, 0);
                const short8 a1 = *(const short8*)(wU1 + (tau * 2 + 1) * 512 + l * 8);
                acc[tau] = __builtin_amdgcn_mfma_f32_16x16x32_bf16(a1, hb1, acc[tau], 0, 0, 0);
            }
        }

        // ---- activation 1: lane owns units u = tt*16 + 4q + reg; gates at tiles tt, 4+tt, 8+tt, 12+tt
        #pragma unroll
        for (int tt = 0; tt < 4; ++tt) {
            float hn[4];
            #pragma unroll
            for (int r = 0; r < 4; ++r) {
                const float iv = fast_sigmoid(acc[tt     ][r]);
                const float fv = fast_sigmoid(acc[4  + tt][r]);
                const float gv = fast_tanh   (acc[8  + tt][r]);
                const float ov = fast_sigmoid(acc[12 + tt][r]);
                const float cn = fmaf(fv, c1[tt][r], iv * gv);
                c1[tt][r] = cn;
                hn[r] = ov * fast_tanh(cn);
            }
            uint2 pw;
            pw.x = pack_bf16x2(hn[0], hn[1]);
            pw.y = pack_bf16x2(hn[2], hn[3]);
            *(uint2*)(h1b + hrow + tt * 16 + q * 4) = pw;   // h1[m][tt*16+4q+0..3]
        }

        // ---- layer 2: acc = b2 + W2^T @ h1_new^T + U2^T @ h2_old^T ----
        {
            const short8 hA0 = *(const short8*)(h1b + hrow + 0  + q * 8);
            const short8 hA1 = *(const short8*)(h1b + hrow + 32 + q * 8);
            const short8 hB0 = *(const short8*)(h2b + hrow + 0  + q * 8);
            const short8 hB1 = *(const short8*)(h2b + hrow + 32 + q * 8);
            #pragma unroll
            for (int tau = 0; tau < 16; ++tau) {
                floatx4 a = b2f[tau];
                const short8 w0 = *(const short8*)(wW2 + (tau * 2 + 0) * 512 + l * 8);
                a = __builtin_amdgcn_mfma_f32_16x16x32_bf16(w0, hA0, a, 0, 0, 0);
                const short8 w1 = *(const short8*)(wW2 + (tau * 2 + 1) * 512 + l * 8);
                a = __builtin_amdgcn_mfma_f32_16x16x32_bf16(w1, hA1, a, 0, 0, 0);
                const short8 u0 = *(const short8*)(wU2 + (tau * 2 + 0) * 512 + l * 8);
                a = __builtin_amdgcn_mfma_f32_16x16x32_bf16(u0, hB0, a, 0, 0, 0);
                const short8 u1 = *(const short8*)(wU2 + (tau * 2 + 1) * 512 + l * 8);
                a = __builtin_amdgcn_mfma_f32_16x16x32_bf16(u1, hB1, a, 0, 0, 0);
                acc[tau] = a;
            }
        }

        // ---- activation 2 -> h2 LDS + h2f regs ----
        #pragma unroll
        for (int tt = 0; tt < 4; ++tt) {
            #pragma unroll
            for (int r = 0; r < 4; ++r) {
                const float iv = fast_sigmoid(acc[tt     ][r]);
                const float fv = fast_sigmoid(acc[4  + tt][r]);
                const float gv = fast_tanh   (acc[8  + tt][r]);
                const float ov = fast_sigmoid(acc[12 + tt][r]);
                const float cn = fmaf(fv, c2[tt][r], iv * gv);
                c2[tt][r] = cn;
                h2f[tt][r] = ov * fast_tanh(cn);
            }
            uint2 pw;
            pw.x = pack_bf16x2(h2f[tt][0], h2f[tt][1]);
            pw.y = pack_bf16x2(h2f[tt][2], h2f[tt][3]);
            *(uint2*)(h2b + hrow + tt * 16 + q * 4) = pw;
        }
    }

    // ---- output: sigmoid(h2 @ Wo + bo); partials over q-groups, reduce across lanes m,m+16,m+32,m+48
    float dot = 0.f;
    #pragma unroll
    for (int tt = 0; tt < 4; ++tt) {
        const floatx4 w = *(const floatx4*)(Wo + tt * 16 + 4 * q);
        dot += h2f[tt][0] * w[0] + h2f[tt][1] * w[1] + h2f[tt][2] * w[2] + h2f[tt][3] * w[3];
    }
    dot += __shfl_xor(dot, 16, 64);
    dot += __shfl_xor(dot, 32, 64);
    if (l < 16) out[b0 + m] = fast_sigmoid(dot + bo[0]);
}

extern "C" void kernel_launch(void* const* d_in, const int* in_sizes, int n_in,
                              void* d_out, int out_size, void* d_ws, size_t ws_size,
                              hipStream_t stream) {
    const int*   tokens = (const int*)  d_in[0];
    const float* emb    = (const float*)d_in[1];
    const float* W1     = (const float*)d_in[2];
    const float* U1     = (const float*)d_in[3];
    const float* b1     = (const float*)d_in[4];   // folded into embW
    const float* W2     = (const float*)d_in[5];
    const float* U2     = (const float*)d_in[6];
    const float* b2     = (const float*)d_in[7];
    const float* Wo     = (const float*)d_in[8];
    const float* bo     = (const float*)d_in[9];
    float* out = (float*)d_out;

    char* ws = (char*)d_ws;
    float*          embWp = (float*)ws;                      // 10,240,000 B
    unsigned short* wrep  = (unsigned short*)(ws + 10240000); // 98,304 B
    (void)in_sizes; (void)n_in; (void)out_size; (void)ws_size;

    embW_kernel<<<TOTAL_WORDS, 256, 0, stream>>>(emb, W1, b1, embWp);
    repack_kernel<<<dim3(64, 3), 256, 0, stream>>>(U1, W2, U2, wrep);

    const int smem_bytes = 102912;  // 96KB weights + 2x 2304B h buffers
    hipFuncSetAttribute((const void*)lstm_main,
                        hipFuncAttributeMaxDynamicSharedMemorySize, smem_bytes);
    lstm_main<<<BATCH / 16, 64, smem_bytes, stream>>>(tokens, embWp, wrep, b2, Wo, bo, out);
}

// Round 13
// 202.004 us; speedup vs baseline: 3.9505x; 2.2311x over previous
//
#include <hip/hip_runtime.h>

#define TOTAL_WORDS 10000
#define EMBED_LEN 100
#define SEQ_LEN 80
#define BATCH 4096
#define UNITS 64

typedef __attribute__((ext_vector_type(8))) short short8;
typedef __attribute__((ext_vector_type(4))) float floatx4;

// ---------- fast activations (no NaN at saturation) ----------
__device__ __forceinline__ float fast_sigmoid(float x) {
    return __builtin_amdgcn_rcpf(1.0f + __builtin_amdgcn_exp2f(-1.4426950408889634f * x));
}
__device__ __forceinline__ float fast_tanh(float x) {
    return fmaf(2.0f, __builtin_amdgcn_rcpf(1.0f + __builtin_amdgcn_exp2f(-2.8853900817779268f * x)), -1.0f);
}
// RNE f32->bf16 pair pack (a -> low16, b -> high16)
__device__ __forceinline__ unsigned int pack_bf16x2(float a, float b) {
    unsigned int ua = __float_as_uint(a), ub = __float_as_uint(b);
    ua = (ua + 0x7FFFu + ((ua >> 16) & 1u)) >> 16;
    ub = (ub + 0x7FFFu + ((ub >> 16) & 1u)) & 0xFFFF0000u;
    return ua | ub;
}

// ---------- embW[v][j] = emb[v]@W1[:,j] + b1[j]; 8 words per block ----------
__global__ __launch_bounds__(256) void embW_kernel(
    const float* __restrict__ emb, const float* __restrict__ W1,
    const float* __restrict__ b1, float* __restrict__ embW)
{
    const int v0 = blockIdx.x * 8;
    const int j = threadIdx.x;
    const float bj = b1[j];
    float acc[8];
    #pragma unroll
    for (int v = 0; v < 8; ++v) acc[v] = bj;
    #pragma unroll 2
    for (int k = 0; k < EMBED_LEN; ++k) {
        const float wk = W1[k * 256 + j];
        #pragma unroll
        for (int v = 0; v < 8; ++v)
            acc[v] = fmaf(emb[(v0 + v) * EMBED_LEN + k], wk, acc[v]);
    }
    #pragma unroll
    for (int v = 0; v < 8; ++v)
        embW[(size_t)(v0 + v) * 256 + j] = acc[v];
}

// ---------- repack U1,W2,U2 (f32 [64][256]) -> bf16 A-fragment-linear ----------
// element e = ((tau*2+kt)*64 + lane)*8 + j8 holds bf16( M[kt*32 + (lane>>4)*8 + j8][tau*16 + (lane&15)] )
__global__ __launch_bounds__(256) void repack_kernel(
    const float* __restrict__ U1, const float* __restrict__ W2,
    const float* __restrict__ U2, unsigned short* __restrict__ wr)
{
    const int e = blockIdx.x * 256 + threadIdx.x;          // 0..16383
    const float* src = (blockIdx.y == 0) ? U1 : ((blockIdx.y == 1) ? W2 : U2);
    const int j8 = e & 7;
    const int l  = (e >> 3) & 63;
    const int kt = (e >> 9) & 1;
    const int tau = e >> 10;
    const int k = kt * 32 + (l >> 4) * 8 + j8;
    const int j = tau * 16 + (l & 15);
    unsigned int u = __float_as_uint(src[k * 256 + j]);
    u = (u + 0x7FFFu + ((u >> 16) & 1u)) >> 16;
    wr[blockIdx.y * 16384 + e] = (unsigned short)u;
}

// ---------- main recurrence ----------
// 16 samples/block, 4 waves/block. Wave w owns output tiles {w,4+w,8+w,12+w}
// = gates i,f,g,o of units w*16..w*16+15. Weights in registers (24 short8/wave).
// h1/h2 double-buffered in LDS (bf16, [16 m][72 u]); 2 barriers/step.
__global__ __launch_bounds__(256) void lstm_main(
    const int*   __restrict__ tokens,
    const float* __restrict__ embW,
    const unsigned short* __restrict__ wr,
    const float* __restrict__ b2,
    const float* __restrict__ Wo,
    const float* __restrict__ bo,
    float*       __restrict__ out)
{
    __shared__ unsigned short h1b[2][1152];   // [buf][m*72+u]
    __shared__ unsigned short h2b[2][1152];
    __shared__ float padf[64];

    const int l = threadIdx.x & 63;
    const int w = threadIdx.x >> 6;           // wave 0..3
    const int m = l & 15, q = l >> 4;
    const int b0 = blockIdx.x * 16;
    const int hrow = m * 72;

    // zero h buffers
    for (int i = threadIdx.x; i < 1152; i += 256) {
        ((unsigned int*)h1b)[i] = 0u;
        ((unsigned int*)h2b)[i] = 0u;
    }

    // ---- load this wave's weight fragments into registers (one-time) ----
    short8 a1w[4][2], w2w[4][2], u2w[4][2];   // [g][kt], tau = g*4+w
    #pragma unroll
    for (int g = 0; g < 4; ++g) {
        const int tau = g * 4 + w;
        #pragma unroll
        for (int kt = 0; kt < 2; ++kt) {
            const int off = (tau * 2 + kt) * 512 + l * 8;
            a1w[g][kt] = *(const short8*)(wr +         off);
            w2w[g][kt] = *(const short8*)(wr + 16384 + off);
            u2w[g][kt] = *(const short8*)(wr + 32768 + off);
        }
    }
    // b2 fragments: tile tau=g*4+w, rows 4q+r -> b2[tau*16+4q+r]
    floatx4 b2f[4];
    #pragma unroll
    for (int g = 0; g < 4; ++g)
        b2f[g] = *(const floatx4*)(b2 + (g * 4 + w) * 16 + 4 * q);

    float c1[4] = {}, c2[4] = {}, h2f[4] = {};

    // t=0 seed gather (cold) + token prefetch
    const int tok0 = tokens[(b0 + m) * SEQ_LEN + 0];
    floatx4 xb[4];
    #pragma unroll
    for (int g = 0; g < 4; ++g)
        xb[g] = *(const floatx4*)(embW + (size_t)tok0 * 256 + (g * 4 + w) * 16 + 4 * q);
    int tokN = tokens[(b0 + m) * SEQ_LEN + 1];

    __syncthreads();   // h buffers zeroed

    // one LSTM step: read h(t-1) from *p buffers, write h(t) to *c buffers
    auto step = [&](const unsigned short* h1p, unsigned short* h1c,
                    const unsigned short* h2p, unsigned short* h2c, int t) {
        // seed acc with prefetched x@W1+b1, then prefetch next step
        floatx4 acc[4];
        #pragma unroll
        for (int g = 0; g < 4; ++g) acc[g] = xb[g];
        #pragma unroll
        for (int g = 0; g < 4; ++g)
            xb[g] = *(const floatx4*)(embW + (size_t)tokN * 256 + (g * 4 + w) * 16 + 4 * q);
        {
            const int tn2 = (t + 2 < SEQ_LEN) ? t + 2 : SEQ_LEN - 1;
            tokN = tokens[(b0 + m) * SEQ_LEN + tn2];
        }

        // ---- layer 1: acc += U1^T @ h1(t-1)^T ----
        {
            const short8 hb0 = *(const short8*)(h1p + hrow + 0  + q * 8);
            const short8 hb1 = *(const short8*)(h1p + hrow + 32 + q * 8);
            #pragma unroll
            for (int g = 0; g < 4; ++g) {
                acc[g] = __builtin_amdgcn_mfma_f32_16x16x32_bf16(a1w[g][0], hb0, acc[g], 0, 0, 0);
                acc[g] = __builtin_amdgcn_mfma_f32_16x16x32_bf16(a1w[g][1], hb1, acc[g], 0, 0, 0);
            }
        }
        // ---- act 1 (units w*16+4q+r) ----
        {
            float hn[4];
            #pragma unroll
            for (int r = 0; r < 4; ++r) {
                const float iv = fast_sigmoid(acc[0][r]);
                const float fv = fast_sigmoid(acc[1][r]);
                const float gv = fast_tanh   (acc[2][r]);
                const float ov = fast_sigmoid(acc[3][r]);
                const float cn = fmaf(fv, c1[r], iv * gv);
                c1[r] = cn;
                hn[r] = ov * fast_tanh(cn);
            }
            uint2 pw;
            pw.x = pack_bf16x2(hn[0], hn[1]);
            pw.y = pack_bf16x2(hn[2], hn[3]);
            *(uint2*)(h1c + hrow + w * 16 + q * 4) = pw;
        }
        __syncthreads();   // h1(t) complete

        // ---- layer 2: acc = b2 + W2^T @ h1(t)^T + U2^T @ h2(t-1)^T ----
        {
            const short8 hA0 = *(const short8*)(h1c + hrow + 0  + q * 8);
            const short8 hA1 = *(const short8*)(h1c + hrow + 32 + q * 8);
            const short8 hB0 = *(const short8*)(h2p + hrow + 0  + q * 8);
            const short8 hB1 = *(const short8*)(h2p + hrow + 32 + q * 8);
            #pragma unroll
            for (int g = 0; g < 4; ++g) {
                floatx4 a = b2f[g];
                a = __builtin_amdgcn_mfma_f32_16x16x32_bf16(w2w[g][0], hA0, a, 0, 0, 0);
                a = __builtin_amdgcn_mfma_f32_16x16x32_bf16(w2w[g][1], hA1, a, 0, 0, 0);
                a = __builtin_amdgcn_mfma_f32_16x16x32_bf16(u2w[g][0], hB0, a, 0, 0, 0);
                a = __builtin_amdgcn_mfma_f32_16x16x32_bf16(u2w[g][1], hB1, a, 0, 0, 0);
                acc[g] = a;
            }
        }
        // ---- act 2 ----
        {
            #pragma unroll
            for (int r = 0; r < 4; ++r) {
                const float iv = fast_sigmoid(acc[0][r]);
                const float fv = fast_sigmoid(acc[1][r]);
                const float gv = fast_tanh   (acc[2][r]);
                const float ov = fast_sigmoid(acc[3][r]);
                const float cn = fmaf(fv, c2[r], iv * gv);
                c2[r] = cn;
                h2f[r] = ov * fast_tanh(cn);
            }
            uint2 pw;
            pw.x = pack_bf16x2(h2f[0], h2f[1]);
            pw.y = pack_bf16x2(h2f[2], h2f[3]);
            *(uint2*)(h2c + hrow + w * 16 + q * 4) = pw;
        }
        __syncthreads();   // h2(t) complete
    };

    // h(t) lives in buffer t&1; h(-1) = zeroed buffer 1
    for (int t = 0; t < SEQ_LEN; t += 2) {
        step(h1b[1], h1b[0], h2b[1], h2b[0], t);       // even t
        step(h1b[0], h1b[1], h2b[0], h2b[1], t + 1);   // odd t
    }

    // ---- output: sigmoid(h2 @ Wo + bo) ----
    const floatx4 wo = *(const floatx4*)(Wo + w * 16 + 4 * q);
    float part = h2f[0] * wo[0] + h2f[1] * wo[1] + h2f[2] * wo[2] + h2f[3] * wo[3];
    part += __shfl_xor(part, 16, 64);
    part += __shfl_xor(part, 32, 64);   // lanes with same m now hold wave-partial
    if (l < 16) padf[w * 16 + m] = part;
    __syncthreads();
    if (threadIdx.x < 16) {
        const int mm = threadIdx.x;
        const float dot = padf[mm] + padf[16 + mm] + padf[32 + mm] + padf[48 + mm];
        out[b0 + mm] = fast_sigmoid(dot + bo[0]);
    }
}

extern "C" void kernel_launch(void* const* d_in, const int* in_sizes, int n_in,
                              void* d_out, int out_size, void* d_ws, size_t ws_size,
                              hipStream_t stream) {
    const int*   tokens = (const int*)  d_in[0];
    const float* emb    = (const float*)d_in[1];
    const float* W1     = (const float*)d_in[2];
    const float* U1     = (const float*)d_in[3];
    const float* b1     = (const float*)d_in[4];   // folded into embW
    const float* W2     = (const float*)d_in[5];
    const float* U2     = (const float*)d_in[6];
    const float* b2     = (const float*)d_in[7];
    const float* Wo     = (const float*)d_in[8];
    const float* bo     = (const float*)d_in[9];
    float* out = (float*)d_out;

    char* ws = (char*)d_ws;
    float*          embWp = (float*)ws;                       // 10,240,000 B
    unsigned short* wrep  = (unsigned short*)(ws + 10240000); // 98,304 B
    (void)in_sizes; (void)n_in; (void)out_size; (void)ws_size;

    embW_kernel<<<TOTAL_WORDS / 8, 256, 0, stream>>>(emb, W1, b1, embWp);
    repack_kernel<<<dim3(64, 3), 256, 0, stream>>>(U1, W2, U2, wrep);
    lstm_main<<<BATCH / 16, 256, 0, stream>>>(tokens, embWp, wrep, b2, Wo, bo, out);
}